// Round 9
// baseline (2962.326 us; speedup 1.0000x reference)
//
#include <hip/hip_runtime.h>

// Problem constants (from reference)
constexpr int T_ = 16, B_ = 32, NI_ = 64, NO_ = 64, H_ = 256, N_ = 2048, M_ = 64, P_ = 198;
constexpr int CH_ = 8;              // chunks (blocks) per batch
constexpr int RPC_ = N_ / CH_;      // 256 rows per chunk
constexpr int NBLK_ = B_ * CH_;     // 256 blocks
constexpr int NTHR_ = 256;

// Workspace float layout
constexpr int OFF_GATES = 0;                       // B*4H    = 32768
constexpr int OFF_H     = OFF_GATES + B_ * 4 * H_; // B*H     = 8192
constexpr int OFF_C     = OFF_H + B_ * H_;         // 2*B*H   = 16384
constexpr int OFF_ES    = OFF_C + 2 * B_ * H_;     // B*N     = 65536
constexpr int OFF_WP    = OFF_ES + B_ * N_;        // B*N
constexpr int OFF_W     = OFF_WP + B_ * N_;        // B*N
constexpr int OFF_SE    = OFF_W + B_ * N_;         // B*CH
constexpr int OFF_SW    = OFF_SE + B_ * CH_;       // B*CH
constexpr int OFF_RP    = OFF_SW + B_ * CH_;       // B*CH*M
constexpr int WS_FLOATS = OFF_RP + B_ * CH_ * M_;  // = 270848
constexpr size_t SLOT_BYTE_OFF = (size_t)WS_FLOATS * 4;
constexpr int NSLOTS = 80;                         // 65 used

__device__ __forceinline__ float sigmf(float x)  { return 1.0f / (1.0f + expf(-x)); }
__device__ __forceinline__ float splusf(float x) { return fmaxf(x, 0.0f) + log1pf(expf(-fabsf(x))); }

// One-shot grid barrier: each sync point uses its own zero-initialized slot.
// Spin is BOUNDED (~0.2s) so a broken co-residency assumption degrades to a
// wrong answer instead of a GPU hang (diagnosable vs container death).
__device__ __forceinline__ void gbar(unsigned* slots, int k) {
  __syncthreads();
  if (threadIdx.x == 0) {
    __threadfence();                                   // agent-scope release
    atomicAdd(&slots[k], 1u);                          // device-scope add
    unsigned spins = 0;
    while (__hip_atomic_load(&slots[k], __ATOMIC_ACQUIRE,
                             __HIP_MEMORY_SCOPE_AGENT) < (unsigned)NBLK_) {
      __builtin_amdgcn_s_sleep(2);
      if (++spins >= (1u << 22)) break;                // safety valve, never hit in healthy runs
    }
  }
  __syncthreads();
  __threadfence();                                     // acquire side, all waves
}

__global__ void __launch_bounds__(NTHR_) ntm_kernel(
    const float* __restrict__ x,   const float* __restrict__ mem0,
    const float* __restrict__ w0,  const float* __restrict__ r0,
    const float* __restrict__ h0,  const float* __restrict__ c0,
    const float* __restrict__ Wih, const float* __restrict__ Whh,
    const float* __restrict__ bih, const float* __restrict__ bhh,
    const float* __restrict__ Wp,  const float* __restrict__ bp,
    const float* __restrict__ Wfc, const float* __restrict__ bfc,
    float* __restrict__ out, float* __restrict__ ws, unsigned* __restrict__ slots)
{
  const int tid  = threadIdx.x;
  const int blk  = blockIdx.x;
  const int b    = blk >> 3;
  const int ch   = blk & 7;
  const int lane = tid & 63;
  const int wave = tid >> 6;
  const int grp  = lane >> 4;        // 4 row-groups per wave
  const int ml   = (lane & 15) * 4;  // m base for float4 slice
  const int n0   = ch * RPC_;
  int bar = 0;

  float* membuf  = out + T_ * B_ * NO_;   // working memory lives in d_out tail
  float* g_gates = ws + OFF_GATES;
  float* g_h  = ws + OFF_H;
  float* g_c  = ws + OFF_C;
  float* g_es = ws + OFF_ES;
  float* g_wp = ws + OFF_WP;
  float* g_w  = ws + OFF_W;
  float* g_se = ws + OFF_SE;
  float* g_sw = ws + OFF_SW;
  float* g_rp = ws + OFF_RP;

  __shared__ float s_r[M_];
  __shared__ float s_h[H_];
  __shared__ float s_p[P_];
  __shared__ float s_kn[M_], s_e[M_], s_a[M_];
  __shared__ float s_scal[8];   // 0:beta 1:g 2..4:s 5:gamma 6:knorm 7:inv-denoms
  __shared__ float s_red[4];
  __shared__ float s_rp[4][M_];

  // ---------------- init: w0 partial sums, copy h0/c0 ----------------
  {
    float v = w0[b * N_ + n0 + tid];
    #pragma unroll
    for (int o = 32; o > 0; o >>= 1) v += __shfl_xor(v, o);
    if (lane == 0) s_red[wave] = v;
    __syncthreads();
    if (tid == 0) g_se[b * CH_ + ch] = s_red[0] + s_red[1] + s_red[2] + s_red[3];
    if (ch == 0) {
      for (int i = tid; i < H_; i += NTHR_) {
        g_h[b * H_ + i] = h0[b * H_ + i];
        g_c[b * H_ + i] = c0[b * H_ + i];   // parity 0
      }
    }
  }
  gbar(slots, bar++);

  for (int t = 0; ; ++t) {
    // ============ PHASE A: r combine, out_{t-1}, gates(t) ============
    if (t == 0) {
      if (tid < M_) s_r[tid] = r0[b * M_ + tid];
      float tot = 0.f;
      for (int c2 = 0; c2 < CH_; ++c2) tot += g_se[b * CH_ + c2];
      float inv = 1.0f / tot;
      g_w[b * N_ + n0 + tid] = w0[b * N_ + n0 + tid] * inv;  // w_init
    } else {
      if (tid < M_) {
        float acc = 0.f;
        #pragma unroll
        for (int c2 = 0; c2 < CH_; ++c2) acc += g_rp[(b * CH_ + c2) * M_ + tid];
        s_r[tid] = acc;   // r_new(t-1)
      }
    }
    __syncthreads();
    if (t > 0 && ch == 0) {
      // out_{t-1} = sigmoid([h(t-1); r(t-1)] @ Wfc^T + bfc)
      for (int j = wave * 16; j < wave * 16 + 16; ++j) {
        float acc = 0.f;
        const float* wr = Wfc + j * (H_ + M_);
        #pragma unroll
        for (int q = 0; q < 4; ++q) acc += g_h[b * H_ + lane + 64 * q] * wr[lane + 64 * q];
        acc += s_r[lane] * wr[H_ + lane];
        #pragma unroll
        for (int o = 32; o > 0; o >>= 1) acc += __shfl_xor(acc, o);
        if (lane == 0) out[(size_t)(t - 1) * B_ * NO_ + b * NO_ + j] = sigmf(acc + bfc[j]);
      }
    }
    if (t == T_) break;
    {
      // gates rows [ch*128, ch*128+128): full 384-dim dot per row, 64-lane coop
      float hv0 = g_h[b * H_ + lane];
      float hv1 = g_h[b * H_ + 64 + lane];
      float hv2 = g_h[b * H_ + 128 + lane];
      float hv3 = g_h[b * H_ + 192 + lane];
      float rv  = s_r[lane];
      float xv  = x[(size_t)t * B_ * NI_ + b * NI_ + lane];
      int row0 = ch * 128 + wave * 32;
      for (int rr = 0; rr < 32; ++rr) {
        int row = row0 + rr;
        const float* wi = Wih + row * 128;
        const float* wh = Whh + row * H_;
        float acc = rv * wi[lane] + xv * wi[64 + lane]
                  + hv0 * wh[lane] + hv1 * wh[64 + lane]
                  + hv2 * wh[128 + lane] + hv3 * wh[192 + lane];
        #pragma unroll
        for (int o = 32; o > 0; o >>= 1) acc += __shfl_xor(acc, o);
        if (lane == 0) g_gates[b * 4 * H_ + row] = acc + bih[row] + bhh[row];
      }
    }
    gbar(slots, bar++);

    // ============ PHASE B: LSTM, p, params, content scores ============
    {
      float gi = g_gates[b * 4 * H_ + tid];
      float gf = g_gates[b * 4 * H_ + H_ + tid];
      float gg = g_gates[b * 4 * H_ + 2 * H_ + tid];
      float go = g_gates[b * 4 * H_ + 3 * H_ + tid];
      float cp = g_c[((t & 1) ? B_ * H_ : 0) + b * H_ + tid];
      float cn = sigmf(gf) * cp + sigmf(gi) * tanhf(gg);
      float hn = sigmf(go) * tanhf(cn);
      s_h[tid] = hn;
      if (ch == 0) {
        g_h[b * H_ + tid] = hn;
        g_c[(((t + 1) & 1) ? B_ * H_ : 0) + b * H_ + tid] = cn;
      }
    }
    __syncthreads();
    if (tid < P_) {
      float acc = bp[tid];
      for (int k = 0; k < H_; ++k) acc += s_h[k] * Wp[k * P_ + tid];
      s_p[tid] = acc;
    }
    __syncthreads();
    if (tid < M_) {
      s_kn[tid] = s_p[tid] + 1e-12f;           // kappa + eps
      s_e[tid]  = sigmf(s_p[70 + tid]);        // e
      s_a[tid]  = tanhf(s_p[134 + tid]);       // a
    }
    if (tid == 0) {
      s_scal[0] = splusf(s_p[64]);             // beta
      s_scal[1] = sigmf(s_p[65]);              // g
      float m3 = fmaxf(s_p[66], fmaxf(s_p[67], s_p[68]));
      float e0 = expf(s_p[66] - m3), e1 = expf(s_p[67] - m3), e2 = expf(s_p[68] - m3);
      float ss = e0 + e1 + e2;
      s_scal[2] = e0 / ss; s_scal[3] = e1 / ss; s_scal[4] = e2 / ss;  // shift s
      s_scal[5] = 1.0f + splusf(s_p[69]);      // gamma
    }
    __syncthreads();
    if (tid == 0) {
      float kk = 0.f;
      for (int m2 = 0; m2 < M_; ++m2) kk += s_kn[m2] * s_kn[m2];
      s_scal[6] = sqrtf(kk);                   // ||kappa+eps||
    }
    __syncthreads();
    {
      const float beta = s_scal[0], knorm = s_scal[6];
      const float* mrd = (t == 0) ? mem0 : membuf;
      float accsum = 0.f;
      float k0 = s_kn[ml], k1 = s_kn[ml + 1], k2 = s_kn[ml + 2], k3 = s_kn[ml + 3];
      for (int it = 0; it < 16; ++it) {
        int row = n0 + wave * 64 + it * 4 + grp;
        const float4 mv = *(const float4*)(mrd + (size_t)(b * N_ + row) * M_ + ml);
        float ax = mv.x + 1e-12f, ay = mv.y + 1e-12f, az = mv.z + 1e-12f, aw = mv.w + 1e-12f;
        float num = ax * k0 + ay * k1 + az * k2 + aw * k3;
        float nm  = ax * ax + ay * ay + az * az + aw * aw;
        #pragma unroll
        for (int o = 1; o < 16; o <<= 1) { num += __shfl_xor(num, o); nm += __shfl_xor(nm, o); }
        if ((lane & 15) == 0) {
          float den = fmaxf(sqrtf(nm) * knorm, 1e-8f);
          float es2 = expf(beta * num / den);     // softmax numerator (no max-sub: |score|<=beta)
          g_es[b * N_ + row] = es2;
          accsum += es2;
        }
      }
      #pragma unroll
      for (int o = 32; o > 0; o >>= 1) accsum += __shfl_xor(accsum, o);
      if (lane == 0) s_red[wave] = accsum;
    }
    __syncthreads();
    if (tid == 0) g_se[b * CH_ + ch] = s_red[0] + s_red[1] + s_red[2] + s_red[3];
    gbar(slots, bar++);

    // ============ PHASE CD: w_c, w_g (+halo), shift, sharpen partials ============
    if (tid == 0) {
      float d = 0.f;
      for (int c2 = 0; c2 < CH_; ++c2) d += g_se[b * CH_ + c2];
      s_scal[7] = 1.0f / d;
    }
    __syncthreads();
    {
      const float invden = s_scal[7], gG = s_scal[1];
      const float sh0 = s_scal[2], sh1 = s_scal[3], sh2 = s_scal[4], gam = s_scal[5];
      int row = n0 + tid;
      int rm  = (row + N_ - 1) & (N_ - 1);
      int rp2 = (row + 1) & (N_ - 1);
      float wgm = gG * g_es[b * N_ + rm]  * invden + (1.0f - gG) * g_w[b * N_ + rm];
      float wg0 = gG * g_es[b * N_ + row] * invden + (1.0f - gG) * g_w[b * N_ + row];
      float wgp = gG * g_es[b * N_ + rp2] * invden + (1.0f - gG) * g_w[b * N_ + rp2];
      float what = sh0 * wgm + sh1 * wg0 + sh2 * wgp;
      float wpv  = expf(gam * logf(what));      // w_hat^gamma, w_hat > 0 strictly
      g_wp[b * N_ + row] = wpv;
      float acc = wpv;
      #pragma unroll
      for (int o = 32; o > 0; o >>= 1) acc += __shfl_xor(acc, o);
      if (lane == 0) s_red[wave] = acc;
    }
    __syncthreads();
    if (tid == 0) g_sw[b * CH_ + ch] = s_red[0] + s_red[1] + s_red[2] + s_red[3];
    gbar(slots, bar++);

    // ============ PHASE E: w_new, mem update, r partials ============
    if (tid == 0) {
      float d = 0.f;
      for (int c2 = 0; c2 < CH_; ++c2) d += g_sw[b * CH_ + c2];
      s_scal[7] = 1.0f / (d + 1e-12f);
    }
    __syncthreads();
    {
      const float invwp = s_scal[7];
      const float* mrd = (t == 0) ? mem0 : membuf;
      float e0 = s_e[ml], e1 = s_e[ml + 1], e2 = s_e[ml + 2], e3 = s_e[ml + 3];
      float a0 = s_a[ml], a1 = s_a[ml + 1], a2 = s_a[ml + 2], a3 = s_a[ml + 3];
      float r0a = 0.f, r1a = 0.f, r2a = 0.f, r3a = 0.f;
      for (int it = 0; it < 16; ++it) {
        int row = n0 + wave * 64 + it * 4 + grp;
        float wn = g_wp[b * N_ + row] * invwp;      // broadcast read
        if ((lane & 15) == 0) g_w[b * N_ + row] = wn;  // becomes w_prev
        size_t base = (size_t)(b * N_ + row) * M_ + ml;
        float4 mv = *(const float4*)(mrd + base);
        r0a += wn * mv.x; r1a += wn * mv.y; r2a += wn * mv.z; r3a += wn * mv.w;
        float4 nv;
        nv.x = mv.x * (1.0f - wn * e0) + wn * a0;
        nv.y = mv.y * (1.0f - wn * e1) + wn * a1;
        nv.z = mv.z * (1.0f - wn * e2) + wn * a2;
        nv.w = mv.w * (1.0f - wn * e3) + wn * a3;
        *(float4*)(membuf + base) = nv;
      }
      r0a += __shfl_xor(r0a, 16); r0a += __shfl_xor(r0a, 32);
      r1a += __shfl_xor(r1a, 16); r1a += __shfl_xor(r1a, 32);
      r2a += __shfl_xor(r2a, 16); r2a += __shfl_xor(r2a, 32);
      r3a += __shfl_xor(r3a, 16); r3a += __shfl_xor(r3a, 32);
      if (lane < 16) {
        s_rp[wave][lane * 4 + 0] = r0a;
        s_rp[wave][lane * 4 + 1] = r1a;
        s_rp[wave][lane * 4 + 2] = r2a;
        s_rp[wave][lane * 4 + 3] = r3a;
      }
    }
    __syncthreads();
    if (tid < M_) {
      g_rp[(b * CH_ + ch) * M_ + tid] =
          s_rp[0][tid] + s_rp[1][tid] + s_rp[2][tid] + s_rp[3][tid];
    }
    gbar(slots, bar++);
  }
}

extern "C" void kernel_launch(void* const* d_in, const int* in_sizes, int n_in,
                              void* d_out, int out_size, void* d_ws, size_t ws_size,
                              hipStream_t stream) {
  const float* x   = (const float*)d_in[0];
  const float* mem = (const float*)d_in[1];
  const float* w0  = (const float*)d_in[2];
  const float* r0  = (const float*)d_in[3];
  const float* h0  = (const float*)d_in[4];
  const float* c0  = (const float*)d_in[5];
  const float* Wih = (const float*)d_in[6];
  const float* Whh = (const float*)d_in[7];
  const float* bih = (const float*)d_in[8];
  const float* bhh = (const float*)d_in[9];
  const float* Wp  = (const float*)d_in[10];
  const float* bp  = (const float*)d_in[11];
  const float* Wfc = (const float*)d_in[12];
  const float* bfc = (const float*)d_in[13];
  float* out = (float*)d_out;
  float* wsp = (float*)d_ws;
  unsigned* slots = (unsigned*)((char*)d_ws + SLOT_BYTE_OFF);

  // zero the one-shot barrier slots (graph-capturable async memset)
  hipMemsetAsync((void*)slots, 0, NSLOTS * sizeof(unsigned), stream);

  hipLaunchKernelGGL(ntm_kernel, dim3(NBLK_), dim3(NTHR_), 0, stream,
                     x, mem, w0, r0, h0, c0, Wih, Whh, bih, bhh,
                     Wp, bp, Wfc, bfc, out, wsp, slots);
}

// Round 10
// 994.378 us; speedup vs baseline: 2.9791x; 2.9791x over previous
//
#include <hip/hip_runtime.h>

// Problem constants
constexpr int T_ = 16, B_ = 32, NI_ = 64, NO_ = 64, H_ = 256, N_ = 2048, M_ = 64, P_ = 198;
constexpr int CH_ = 8, RPC_ = N_ / CH_, NBLK_ = B_ * CH_, NTHR_ = 256;
constexpr int ARRIVE_ = 8;   // per-batch barrier: 8 blocks

// Workspace float layout (cross-block shared arrays only)
constexpr int OFF_GATES = 0;                      // B*4H = 32768
constexpr int OFF_SE = OFF_GATES + B_ * 4 * H_;   // B*8
constexpr int OFF_SW = OFF_SE + B_ * CH_;         // B*8
constexpr int OFF_RP = OFF_SW + B_ * CH_;         // B*8*64
constexpr int OFF_HE = OFF_RP + B_ * CH_ * M_;    // B*16 es halo
constexpr int OFF_HW = OFF_HE + B_ * 2 * CH_;     // B*16 w halo
constexpr int WS_FLOATS = OFF_HW + B_ * 2 * CH_;  // 50688
constexpr size_t SLOT_BYTE_OFF = (size_t)WS_FLOATS * 4;
constexpr int NPHASE = 1 + 3 * T_;                // 49 barriers
constexpr int NSLOTS = NPHASE * B_;               // per-batch slots

__device__ __forceinline__ float sigmf(float x)  { return 1.0f / (1.0f + expf(-x)); }
__device__ __forceinline__ float splusf(float x) { return fmaxf(x, 0.0f) + log1pf(expf(-fabsf(x))); }

// Coherent (agent-scope) accesses: bypass stale caches, NO L2 flush/invalidate.
__device__ __forceinline__ float cload(const float* p) {
  return __hip_atomic_load(p, __ATOMIC_RELAXED, __HIP_MEMORY_SCOPE_AGENT);
}
__device__ __forceinline__ void cstore(float* p, float v) {
  __hip_atomic_store(p, v, __ATOMIC_RELAXED, __HIP_MEMORY_SCOPE_AGENT);
}

// Per-batch one-shot barrier (8 arrivals). hipcc drains vmcnt before s_barrier,
// so all of this block's coherent stores are globally visible before the add.
// Bounded spin: failure degrades to wrong answer, not a hang.
__device__ __forceinline__ void gbar(unsigned* slots, int k, int b) {
  __syncthreads();
  if (threadIdx.x == 0) {
    unsigned* s = &slots[k * B_ + b];
    __hip_atomic_fetch_add(s, 1u, __ATOMIC_RELAXED, __HIP_MEMORY_SCOPE_AGENT);
    unsigned spins = 0;
    while (__hip_atomic_load(s, __ATOMIC_RELAXED, __HIP_MEMORY_SCOPE_AGENT) < (unsigned)ARRIVE_) {
      __builtin_amdgcn_s_sleep(2);
      if (++spins >= (1u << 22)) break;
    }
    asm volatile("" ::: "memory");
  }
  __syncthreads();
}

__global__ void __launch_bounds__(NTHR_) ntm_kernel(
    const float* __restrict__ x,   const float* __restrict__ mem0,
    const float* __restrict__ w0,  const float* __restrict__ r0,
    const float* __restrict__ h0,  const float* __restrict__ c0,
    const float* __restrict__ Wih, const float* __restrict__ Whh,
    const float* __restrict__ bih, const float* __restrict__ bhh,
    const float* __restrict__ Wp,  const float* __restrict__ bp,
    const float* __restrict__ Wfc, const float* __restrict__ bfc,
    float* __restrict__ out, float* __restrict__ ws, unsigned* __restrict__ slots)
{
  const int tid  = threadIdx.x;
  const int blk  = blockIdx.x;
  const int b    = blk >> 3;
  const int ch   = blk & 7;
  const int lane = tid & 63;
  const int wave = tid >> 6;
  const int q    = tid & 3;        // col-slice [16q,16q+16)
  const int rb   = tid >> 2;       // local row base 0..63 (rows rb+64k)
  const int n0   = ch * RPC_;
  int bar = 0;

  float* membuf  = out + T_ * B_ * NO_;
  float* g_gates = ws + OFF_GATES;
  float* g_se = ws + OFF_SE;
  float* g_sw = ws + OFF_SW;
  float* g_rp = ws + OFF_RP;
  float* g_he = ws + OFF_HE;
  float* g_hw = ws + OFF_HW;

  __shared__ float s_h[H_], s_c[H_], s_r[M_], s_p[P_];
  __shared__ float s_kn[M_], s_e[M_], s_a[M_];
  __shared__ float s_es[RPC_ + 2], s_wn[RPC_ + 2], s_wpA[RPC_];
  __shared__ float s_scal[8];  // 0:beta 1:g 2..4:s 5:gamma 6:knorm/invSwp 7:invden
  __shared__ float s_red[4];
  __shared__ float s_rp[4][M_];

  // mem chunk in REGISTERS: 4 quarter-rows (rows rb+64k, cols 16q..16q+15)
  float mreg[4][16];

  // ---------------- init ----------------
  {
    const float* src = mem0 + ((size_t)b * N_ + n0) * M_;
    #pragma unroll
    for (int k = 0; k < 4; ++k) {
      #pragma unroll
      for (int f = 0; f < 4; ++f) {
        float4 v = *(const float4*)(src + (rb + 64 * k) * M_ + q * 16 + 4 * f);
        mreg[k][4*f+0] = v.x; mreg[k][4*f+1] = v.y; mreg[k][4*f+2] = v.z; mreg[k][4*f+3] = v.w;
      }
    }
    s_h[tid] = h0[b * H_ + tid];
    s_c[tid] = c0[b * H_ + tid];
    float v = w0[b * N_ + n0 + tid];
    #pragma unroll
    for (int o = 32; o > 0; o >>= 1) v += __shfl_xor(v, o);
    if (lane == 0) s_red[wave] = v;
    __syncthreads();
    if (tid == 0) cstore(&g_sw[b * CH_ + ch], s_red[0] + s_red[1] + s_red[2] + s_red[3]);
  }
  gbar(slots, bar++, b);

  float wp_reg = 0.f;  // wp of row tid, carried CD -> next A'

  for (int t = 0; ; ++t) {
    // ===== PHASE A': r, w_new, mem-update(t-1), out_{t-1}, gates(t) =====
    if (t == 0) {
      if (tid < M_) s_r[tid] = r0[b * M_ + tid];
      if (tid == 64) {
        float d = 0.f;
        for (int c2 = 0; c2 < CH_; ++c2) d += cload(&g_sw[b * CH_ + c2]);
        s_scal[6] = 1.0f / d;
      }
      __syncthreads();
      s_wn[1 + tid] = w0[b * N_ + n0 + tid] * s_scal[6];   // w_init
    } else {
      float racc = 0.f;
      if (tid < M_) {
        #pragma unroll
        for (int c2 = 0; c2 < CH_; ++c2) racc += cload(&g_rp[(b * CH_ + c2) * M_ + tid]);
      }
      if (tid == 64) {
        float d = 0.f;
        for (int c2 = 0; c2 < CH_; ++c2) d += cload(&g_sw[b * CH_ + c2]);
        s_scal[6] = 1.0f / (d + 1e-12f);
      }
      __syncthreads();
      float inv = s_scal[6];
      if (tid < M_) s_r[tid] = racc * inv;   // r_{t-1}
      s_wn[1 + tid] = wp_reg * inv;          // w_{t-1} normalized
    }
    __syncthreads();
    if (tid == 0) {
      cstore(&g_hw[b * 2 * CH_ + 2 * ch + 0], s_wn[1]);
      cstore(&g_hw[b * 2 * CH_ + 2 * ch + 1], s_wn[RPC_]);
    }
    if (t > 0) {
      // mem update (step t-1), pure register math
      #pragma unroll
      for (int k = 0; k < 4; ++k) {
        float wn = s_wn[1 + rb + 64 * k];
        #pragma unroll
        for (int j = 0; j < 16; ++j) {
          int m = q * 16 + j;
          mreg[k][j] = mreg[k][j] * (1.0f - wn * s_e[m]) + wn * s_a[m];
        }
      }
      if (ch == 0) {
        // out_{t-1} = sigmoid([h;r] @ Wfc^T + bfc)
        for (int j = wave * 16; j < wave * 16 + 16; ++j) {
          float acc = 0.f;
          const float* wr = Wfc + j * (H_ + M_);
          #pragma unroll
          for (int qq = 0; qq < 4; ++qq) acc += s_h[lane + 64 * qq] * wr[lane + 64 * qq];
          acc += s_r[lane] * wr[H_ + lane];
          #pragma unroll
          for (int o = 32; o > 0; o >>= 1) acc += __shfl_xor(acc, o);
          if (lane == 0) out[(size_t)(t - 1) * B_ * NO_ + b * NO_ + j] = sigmf(acc + bfc[j]);
        }
      }
    }
    if (t == T_) break;
    {
      // gates rows [ch*128, +128), wave-coop 64-lane dots (weights L2-resident)
      float hv0 = s_h[lane], hv1 = s_h[64 + lane], hv2 = s_h[128 + lane], hv3 = s_h[192 + lane];
      float rv = s_r[lane];
      float xv = x[(size_t)t * B_ * NI_ + b * NI_ + lane];
      int row0 = ch * 128 + wave * 32;
      for (int rr = 0; rr < 32; ++rr) {
        int row = row0 + rr;
        const float* wi = Wih + row * 128;
        const float* wh = Whh + row * H_;
        float acc = rv * wi[lane] + xv * wi[64 + lane]
                  + hv0 * wh[lane] + hv1 * wh[64 + lane]
                  + hv2 * wh[128 + lane] + hv3 * wh[192 + lane];
        #pragma unroll
        for (int o = 32; o > 0; o >>= 1) acc += __shfl_xor(acc, o);
        if (lane == 0) cstore(&g_gates[b * 4 * H_ + row], acc + bih[row] + bhh[row]);
      }
    }
    gbar(slots, bar++, b);

    // ===== PHASE B: LSTM, p, params, content scores =====
    {
      float gi = cload(&g_gates[b * 4 * H_ + tid]);
      float gf = cload(&g_gates[b * 4 * H_ + H_ + tid]);
      float gg = cload(&g_gates[b * 4 * H_ + 2 * H_ + tid]);
      float go = cload(&g_gates[b * 4 * H_ + 3 * H_ + tid]);
      float cn = sigmf(gf) * s_c[tid] + sigmf(gi) * tanhf(gg);
      float hn = sigmf(go) * tanhf(cn);
      s_c[tid] = cn;
      s_h[tid] = hn;
    }
    __syncthreads();
    if (tid < P_) {
      float acc = bp[tid];
      for (int k = 0; k < H_; ++k) acc += s_h[k] * Wp[k * P_ + tid];
      s_p[tid] = acc;
    }
    __syncthreads();
    if (tid < M_) {
      s_kn[tid] = s_p[tid] + 1e-12f;
      s_e[tid]  = sigmf(s_p[70 + tid]);
      s_a[tid]  = tanhf(s_p[134 + tid]);
    }
    if (tid == 0) {
      s_scal[0] = splusf(s_p[64]);
      s_scal[1] = sigmf(s_p[65]);
      float m3 = fmaxf(s_p[66], fmaxf(s_p[67], s_p[68]));
      float e0 = expf(s_p[66] - m3), e1 = expf(s_p[67] - m3), e2 = expf(s_p[68] - m3);
      float ss = e0 + e1 + e2;
      s_scal[2] = e0 / ss; s_scal[3] = e1 / ss; s_scal[4] = e2 / ss;
      s_scal[5] = 1.0f + splusf(s_p[69]);
      float kk = 0.f;
      for (int m = 0; m < M_; ++m) { float kv = s_p[m] + 1e-12f; kk += kv * kv; }
      s_scal[6] = sqrtf(kk);     // ||kappa+eps||
    }
    __syncthreads();
    {
      const float beta = s_scal[0], knorm = s_scal[6];
      float accsum = 0.f;
      #pragma unroll
      for (int k = 0; k < 4; ++k) {
        float dot = 0.f, nm = 0.f;
        #pragma unroll
        for (int j = 0; j < 16; ++j) {
          float mv = mreg[k][j] + 1e-12f;
          dot += mv * s_kn[q * 16 + j];
          nm  += mv * mv;
        }
        dot += __shfl_xor(dot, 1); dot += __shfl_xor(dot, 2);
        nm  += __shfl_xor(nm, 1);  nm  += __shfl_xor(nm, 2);
        if (q == 0) {
          float den = fmaxf(sqrtf(nm) * knorm, 1e-8f);
          float es = expf(beta * dot / den);
          s_es[1 + rb + 64 * k] = es;
          accsum += es;
        }
      }
      #pragma unroll
      for (int o = 32; o > 0; o >>= 1) accsum += __shfl_xor(accsum, o);
      if (lane == 0) s_red[wave] = accsum;
    }
    __syncthreads();
    if (tid == 0) {
      cstore(&g_se[b * CH_ + ch], s_red[0] + s_red[1] + s_red[2] + s_red[3]);
      cstore(&g_he[b * 2 * CH_ + 2 * ch + 0], s_es[1]);          // boundary es
      cstore(&g_he[b * 2 * CH_ + 2 * ch + 1], s_es[RPC_]);
    }
    gbar(slots, bar++, b);

    // ===== PHASE CD: w_c, w_g (+halo), shift, sharpen, rp' partials =====
    if (tid == 0) {
      int lch = (ch + 7) & 7, rch = (ch + 1) & 7;
      s_es[0]        = cload(&g_he[b * 2 * CH_ + 2 * lch + 1]);
      s_es[RPC_ + 1] = cload(&g_he[b * 2 * CH_ + 2 * rch + 0]);
      s_wn[0]        = cload(&g_hw[b * 2 * CH_ + 2 * lch + 1]);
      s_wn[RPC_ + 1] = cload(&g_hw[b * 2 * CH_ + 2 * rch + 0]);
      float d = 0.f;
      for (int c2 = 0; c2 < CH_; ++c2) d += cload(&g_se[b * CH_ + c2]);
      s_scal[7] = 1.0f / d;
    }
    __syncthreads();
    {
      const float invden = s_scal[7], gG = s_scal[1];
      const float sh0 = s_scal[2], sh1 = s_scal[3], sh2 = s_scal[4], gam = s_scal[5];
      float wgm = gG * s_es[tid]     * invden + (1.0f - gG) * s_wn[tid];
      float wg0 = gG * s_es[tid + 1] * invden + (1.0f - gG) * s_wn[tid + 1];
      float wgp = gG * s_es[tid + 2] * invden + (1.0f - gG) * s_wn[tid + 2];
      float what = sh0 * wgm + sh1 * wg0 + sh2 * wgp;
      wp_reg = expf(gam * logf(what));   // w_hat^gamma (unnormalized; carried to A')
      s_wpA[tid] = wp_reg;
      float acc = wp_reg;
      #pragma unroll
      for (int o = 32; o > 0; o >>= 1) acc += __shfl_xor(acc, o);
      if (lane == 0) s_red[wave] = acc;
    }
    __syncthreads();
    if (tid == 0) cstore(&g_sw[b * CH_ + ch], s_red[0] + s_red[1] + s_red[2] + s_red[3]);
    {
      // rp'[m] = sum_rows wp*mem_old  (register butterfly, no scratch: ternary selects)
      float v[16];
      #pragma unroll
      for (int j = 0; j < 16; ++j) v[j] = 0.f;
      #pragma unroll
      for (int k = 0; k < 4; ++k) {
        float wp = s_wpA[rb + 64 * k];
        #pragma unroll
        for (int j = 0; j < 16; ++j) v[j] += wp * mreg[k][j];
      }
      #pragma unroll
      for (int a = 0; a < 4; ++a) {
        const int bit = 2 + a;
        int myb = (lane >> bit) & 1;
        const int L = 16 >> (a + 1);
        float nv[8];
        #pragma unroll
        for (int j2 = 0; j2 < L; ++j2) {
          float keep = myb ? v[2 * j2 + 1] : v[2 * j2];
          float send = myb ? v[2 * j2]     : v[2 * j2 + 1];
          float got  = __shfl_xor(send, 1 << bit);
          nv[j2] = keep + got;
        }
        #pragma unroll
        for (int j2 = 0; j2 < L; ++j2) v[j2] = nv[j2];
      }
      s_rp[wave][16 * (lane & 3) + (lane >> 2)] = v[0];
    }
    __syncthreads();
    if (tid < M_) {
      float rv = s_rp[0][tid] + s_rp[1][tid] + s_rp[2][tid] + s_rp[3][tid];
      cstore(&g_rp[(b * CH_ + ch) * M_ + tid], rv);
    }
    gbar(slots, bar++, b);
  }

  // ---------------- final: store mem registers to d_out tail ----------------
  {
    float* dst = membuf + ((size_t)b * N_ + n0) * M_;
    #pragma unroll
    for (int k = 0; k < 4; ++k) {
      #pragma unroll
      for (int f = 0; f < 4; ++f) {
        float4 vv = make_float4(mreg[k][4*f], mreg[k][4*f+1], mreg[k][4*f+2], mreg[k][4*f+3]);
        *(float4*)(dst + (rb + 64 * k) * M_ + q * 16 + 4 * f) = vv;
      }
    }
  }
}

extern "C" void kernel_launch(void* const* d_in, const int* in_sizes, int n_in,
                              void* d_out, int out_size, void* d_ws, size_t ws_size,
                              hipStream_t stream) {
  const float* x   = (const float*)d_in[0];
  const float* mem = (const float*)d_in[1];
  const float* w0  = (const float*)d_in[2];
  const float* r0  = (const float*)d_in[3];
  const float* h0  = (const float*)d_in[4];
  const float* c0  = (const float*)d_in[5];
  const float* Wih = (const float*)d_in[6];
  const float* Whh = (const float*)d_in[7];
  const float* bih = (const float*)d_in[8];
  const float* bhh = (const float*)d_in[9];
  const float* Wp  = (const float*)d_in[10];
  const float* bp  = (const float*)d_in[11];
  const float* Wfc = (const float*)d_in[12];
  const float* bfc = (const float*)d_in[13];
  float* out = (float*)d_out;
  float* wsp = (float*)d_ws;
  unsigned* slots = (unsigned*)((char*)d_ws + SLOT_BYTE_OFF);

  hipMemsetAsync((void*)slots, 0, NSLOTS * sizeof(unsigned), stream);

  hipLaunchKernelGGL(ntm_kernel, dim3(NBLK_), dim3(NTHR_), 0, stream,
                     x, mem, w0, r0, h0, c0, Wih, Whh, bih, bhh,
                     Wp, bp, Wfc, bfc, out, wsp, slots);
}

// Round 11
// 746.265 us; speedup vs baseline: 3.9695x; 1.3325x over previous
//
#include <hip/hip_runtime.h>

// Problem constants
constexpr int T_ = 16, B_ = 32, NI_ = 64, NO_ = 64, H_ = 256, N_ = 2048, M_ = 64, P_ = 198;
constexpr int CH_ = 8, RPC_ = N_ / CH_, NBLK_ = B_ * CH_, NTHR_ = 256;

// Workspace float layout. Per-(b,ch) slots padded to 64B (stride 16 floats)
// to kill cross-XCD false sharing.
constexpr int OFF_GATES = 0;                       // B*4H = 32768 (blocks write disjoint 512B)
constexpr int OFF_SE = OFF_GATES + B_ * 4 * H_;    // B*CH*16 = 4096
constexpr int OFF_SW = OFF_SE + B_ * CH_ * 16;     // 4096
constexpr int OFF_HE = OFF_SW + B_ * CH_ * 16;     // 4096 (2 floats used / slot)
constexpr int OFF_HW = OFF_HE + B_ * CH_ * 16;     // 4096
constexpr int OFF_RP = OFF_HW + B_ * CH_ * 16;     // B*CH*64 = 16384 (256B own lines)
constexpr int WS_FLOATS = OFF_RP + B_ * CH_ * M_;  // 65536
constexpr size_t FLAG_BYTE_OFF = (size_t)WS_FLOATS * 4;  // 262144, 256B-aligned
constexpr int FLAG_STRIDE_U = 64;                  // 256B per block flag line
constexpr size_t FLAG_BYTES = (size_t)NBLK_ * FLAG_STRIDE_U * 4;  // 64KB

__device__ __forceinline__ float sigmf(float x)  { return 1.0f / (1.0f + expf(-x)); }
__device__ __forceinline__ float splusf(float x) { return fmaxf(x, 0.0f) + log1pf(expf(-fabsf(x))); }

// Agent-scope coherent accesses (bypass stale L1/L2, no cache flush).
__device__ __forceinline__ float cload(const float* p) {
  return __hip_atomic_load(p, __ATOMIC_RELAXED, __HIP_MEMORY_SCOPE_AGENT);
}
__device__ __forceinline__ void cstore(float* p, float v) {
  __hip_atomic_store(p, v, __ATOMIC_RELAXED, __HIP_MEMORY_SCOPE_AGENT);
}
__device__ __forceinline__ unsigned cloadu(const unsigned* p) {
  return __hip_atomic_load(p, __ATOMIC_RELAXED, __HIP_MEMORY_SCOPE_AGENT);
}

// RMW-free per-batch barrier. Each block owns a padded flag line and stores a
// monotonically increasing phase counter. Lanes 0-7 of wave 0 poll the batch's
// 8 flags in parallel. __syncthreads() before the store drains vmcnt, so all
// prior cstores are visible before the flag advances (proven by R10 passing).
// Bounded spin: failure degrades to wrong answer, never a hang.
__device__ __forceinline__ void gbar(unsigned* flags, int target, int b, int ch) {
  __syncthreads();
  const int tid = threadIdx.x;
  if (tid == 0) {
    __hip_atomic_store(&flags[(b * CH_ + ch) * FLAG_STRIDE_U], (unsigned)target,
                       __ATOMIC_RELAXED, __HIP_MEMORY_SCOPE_AGENT);
  }
  if (tid < 64) {
    unsigned spins = 0;
    for (;;) {
      unsigned v = (tid < CH_) ? cloadu(&flags[(b * CH_ + tid) * FLAG_STRIDE_U]) : 0xFFFFFFFFu;
      if (__all((tid < CH_) ? (v >= (unsigned)target) : 1)) break;
      __builtin_amdgcn_s_sleep(1);
      if (++spins >= (1u << 20)) break;
    }
    asm volatile("" ::: "memory");
  }
  __syncthreads();
}

__global__ void __launch_bounds__(NTHR_) ntm_kernel(
    const float* __restrict__ x,   const float* __restrict__ mem0,
    const float* __restrict__ w0,  const float* __restrict__ r0,
    const float* __restrict__ h0,  const float* __restrict__ c0,
    const float* __restrict__ Wih, const float* __restrict__ Whh,
    const float* __restrict__ bih, const float* __restrict__ bhh,
    const float* __restrict__ Wp,  const float* __restrict__ bp,
    const float* __restrict__ Wfc, const float* __restrict__ bfc,
    float* __restrict__ out, float* __restrict__ ws, unsigned* __restrict__ flags)
{
  const int tid  = threadIdx.x;
  const int blk  = blockIdx.x;
  const int b    = blk >> 3;
  const int ch   = blk & 7;
  const int lane = tid & 63;
  const int wave = tid >> 6;
  const int q    = tid & 3;        // col-slice [16q,16q+16)
  const int rb   = tid >> 2;       // local row base 0..63 (rows rb+64k)
  const int n0   = ch * RPC_;
  int bar = 1;

  float* membuf  = out + T_ * B_ * NO_;
  float* g_gates = ws + OFF_GATES;
  float* g_se = ws + OFF_SE;
  float* g_sw = ws + OFF_SW;
  float* g_he = ws + OFF_HE;
  float* g_hw = ws + OFF_HW;
  float* g_rp = ws + OFF_RP;

  __shared__ float s_h[H_], s_c[H_], s_r[M_], s_p[P_];
  __shared__ float s_kn[M_], s_e[M_], s_a[M_];
  __shared__ float s_es[RPC_ + 2], s_wn[RPC_ + 2], s_wpA[RPC_];
  __shared__ float s_scal[8];  // 0:beta 1:g 2..4:s 5:gamma 6:knorm/invSwp 7:invden
  __shared__ float s_red[4];
  __shared__ float s_rp[4][M_];

  // mem chunk in REGISTERS: 4 quarter-rows (rows rb+64k, cols 16q..16q+15)
  float mreg[4][16];

  // ---------------- init ----------------
  {
    const float* src = mem0 + ((size_t)b * N_ + n0) * M_;
    #pragma unroll
    for (int k = 0; k < 4; ++k) {
      #pragma unroll
      for (int f = 0; f < 4; ++f) {
        float4 v = *(const float4*)(src + (rb + 64 * k) * M_ + q * 16 + 4 * f);
        mreg[k][4*f+0] = v.x; mreg[k][4*f+1] = v.y; mreg[k][4*f+2] = v.z; mreg[k][4*f+3] = v.w;
      }
    }
    s_h[tid] = h0[b * H_ + tid];
    s_c[tid] = c0[b * H_ + tid];
    float v = w0[b * N_ + n0 + tid];
    #pragma unroll
    for (int o = 32; o > 0; o >>= 1) v += __shfl_xor(v, o);
    if (lane == 0) s_red[wave] = v;
    __syncthreads();
    if (tid == 0) cstore(&g_sw[(b * CH_ + ch) * 16], s_red[0] + s_red[1] + s_red[2] + s_red[3]);
  }
  gbar(flags, bar++, b, ch);

  float wp_reg = 0.f;  // wp of row tid, carried CD -> next A'

  for (int t = 0; ; ++t) {
    // ===== PHASE A': r, w_new, mem-update(t-1), out_{t-1}, gates(t) =====
    if (t == 0) {
      if (tid < M_) s_r[tid] = r0[b * M_ + tid];
      if (tid == 64) {
        float d = 0.f;
        #pragma unroll
        for (int c2 = 0; c2 < CH_; ++c2) d += cload(&g_sw[(b * CH_ + c2) * 16]);
        s_scal[6] = 1.0f / d;
      }
      __syncthreads();
      s_wn[1 + tid] = w0[b * N_ + n0 + tid] * s_scal[6];   // w_init
    } else {
      float racc = 0.f;
      if (tid < M_) {
        #pragma unroll
        for (int c2 = 0; c2 < CH_; ++c2) racc += cload(&g_rp[(b * CH_ + c2) * M_ + tid]);
      }
      if (tid == 64) {
        float d = 0.f;
        #pragma unroll
        for (int c2 = 0; c2 < CH_; ++c2) d += cload(&g_sw[(b * CH_ + c2) * 16]);
        s_scal[6] = 1.0f / (d + 1e-12f);
      }
      __syncthreads();
      float inv = s_scal[6];
      if (tid < M_) s_r[tid] = racc * inv;   // r_{t-1}
      s_wn[1 + tid] = wp_reg * inv;          // w_{t-1} normalized
    }
    __syncthreads();
    if (tid == 0) {
      cstore(&g_hw[(b * CH_ + ch) * 16 + 0], s_wn[1]);
      cstore(&g_hw[(b * CH_ + ch) * 16 + 1], s_wn[RPC_]);
    }
    if (t > 0) {
      // mem update (step t-1), pure register math
      #pragma unroll
      for (int k = 0; k < 4; ++k) {
        float wn = s_wn[1 + rb + 64 * k];
        #pragma unroll
        for (int j = 0; j < 16; ++j) {
          int m = q * 16 + j;
          mreg[k][j] = mreg[k][j] * (1.0f - wn * s_e[m]) + wn * s_a[m];
        }
      }
      if (ch == 0) {
        // out_{t-1} = sigmoid([h;r] @ Wfc^T + bfc)
        for (int j = wave * 16; j < wave * 16 + 16; ++j) {
          float acc = 0.f;
          const float* wr = Wfc + j * (H_ + M_);
          #pragma unroll
          for (int qq = 0; qq < 4; ++qq) acc += s_h[lane + 64 * qq] * wr[lane + 64 * qq];
          acc += s_r[lane] * wr[H_ + lane];
          #pragma unroll
          for (int o = 32; o > 0; o >>= 1) acc += __shfl_xor(acc, o);
          if (lane == 0) out[(size_t)(t - 1) * B_ * NO_ + b * NO_ + j] = sigmf(acc + bfc[j]);
        }
      }
    }
    if (t == T_) break;
    {
      // gates rows [ch*128, +128), wave-coop 64-lane dots (weights L2-resident)
      float hv0 = s_h[lane], hv1 = s_h[64 + lane], hv2 = s_h[128 + lane], hv3 = s_h[192 + lane];
      float rv = s_r[lane];
      float xv = x[(size_t)t * B_ * NI_ + b * NI_ + lane];
      int row0 = ch * 128 + wave * 32;
      for (int rr = 0; rr < 32; ++rr) {
        int row = row0 + rr;
        const float* wi = Wih + row * 128;
        const float* wh = Whh + row * H_;
        float acc = rv * wi[lane] + xv * wi[64 + lane]
                  + hv0 * wh[lane] + hv1 * wh[64 + lane]
                  + hv2 * wh[128 + lane] + hv3 * wh[192 + lane];
        #pragma unroll
        for (int o = 32; o > 0; o >>= 1) acc += __shfl_xor(acc, o);
        if (lane == 0) cstore(&g_gates[b * 4 * H_ + row], acc + bih[row] + bhh[row]);
      }
    }
    gbar(flags, bar++, b, ch);

    // ===== PHASE B: LSTM, p, params, content scores =====
    {
      float gi = cload(&g_gates[b * 4 * H_ + tid]);
      float gf = cload(&g_gates[b * 4 * H_ + H_ + tid]);
      float gg = cload(&g_gates[b * 4 * H_ + 2 * H_ + tid]);
      float go = cload(&g_gates[b * 4 * H_ + 3 * H_ + tid]);
      float cn = sigmf(gf) * s_c[tid] + sigmf(gi) * tanhf(gg);
      float hn = sigmf(go) * tanhf(cn);
      s_c[tid] = cn;
      s_h[tid] = hn;
    }
    __syncthreads();
    if (tid < P_) {
      // 4-way split accumulators: break the 256-FMA dependent chain
      float a0 = 0.f, a1 = 0.f, a2 = 0.f, a3 = 0.f;
      for (int k = 0; k < H_; k += 4) {
        a0 += s_h[k]     * Wp[k * P_ + tid];
        a1 += s_h[k + 1] * Wp[(k + 1) * P_ + tid];
        a2 += s_h[k + 2] * Wp[(k + 2) * P_ + tid];
        a3 += s_h[k + 3] * Wp[(k + 3) * P_ + tid];
      }
      s_p[tid] = bp[tid] + ((a0 + a1) + (a2 + a3));
    }
    __syncthreads();
    if (tid < M_) {
      s_kn[tid] = s_p[tid] + 1e-12f;
      s_e[tid]  = sigmf(s_p[70 + tid]);
      s_a[tid]  = tanhf(s_p[134 + tid]);
    }
    if (wave == 0) {
      // wave-parallel ||kappa+eps||
      float kv = s_p[lane] + 1e-12f;
      float kk = kv * kv;
      #pragma unroll
      for (int o = 32; o > 0; o >>= 1) kk += __shfl_xor(kk, o);
      if (lane == 0) s_scal[6] = sqrtf(kk);
    }
    if (tid == 0) {
      s_scal[0] = splusf(s_p[64]);
      s_scal[1] = sigmf(s_p[65]);
      float m3 = fmaxf(s_p[66], fmaxf(s_p[67], s_p[68]));
      float e0 = expf(s_p[66] - m3), e1 = expf(s_p[67] - m3), e2 = expf(s_p[68] - m3);
      float ss = e0 + e1 + e2;
      s_scal[2] = e0 / ss; s_scal[3] = e1 / ss; s_scal[4] = e2 / ss;
      s_scal[5] = 1.0f + splusf(s_p[69]);
    }
    __syncthreads();
    {
      const float beta = s_scal[0], knorm = s_scal[6];
      float accsum = 0.f;
      #pragma unroll
      for (int k = 0; k < 4; ++k) {
        float dot = 0.f, nm = 0.f;
        #pragma unroll
        for (int j = 0; j < 16; ++j) {
          float mv = mreg[k][j] + 1e-12f;
          dot += mv * s_kn[q * 16 + j];
          nm  += mv * mv;
        }
        dot += __shfl_xor(dot, 1); dot += __shfl_xor(dot, 2);
        nm  += __shfl_xor(nm, 1);  nm  += __shfl_xor(nm, 2);
        if (q == 0) {
          float den = fmaxf(sqrtf(nm) * knorm, 1e-8f);
          float es = expf(beta * dot / den);
          s_es[1 + rb + 64 * k] = es;
          accsum += es;
        }
      }
      #pragma unroll
      for (int o = 32; o > 0; o >>= 1) accsum += __shfl_xor(accsum, o);
      if (lane == 0) s_red[wave] = accsum;
    }
    __syncthreads();
    if (tid == 0) {
      cstore(&g_se[(b * CH_ + ch) * 16], s_red[0] + s_red[1] + s_red[2] + s_red[3]);
      cstore(&g_he[(b * CH_ + ch) * 16 + 0], s_es[1]);
      cstore(&g_he[(b * CH_ + ch) * 16 + 1], s_es[RPC_]);
    }
    gbar(flags, bar++, b, ch);

    // ===== PHASE CD: w_c, w_g (+halo), shift, sharpen, rp' partials =====
    if (tid == 0) {
      int lch = (ch + 7) & 7, rch = (ch + 1) & 7;
      s_es[0]        = cload(&g_he[(b * CH_ + lch) * 16 + 1]);
      s_es[RPC_ + 1] = cload(&g_he[(b * CH_ + rch) * 16 + 0]);
      s_wn[0]        = cload(&g_hw[(b * CH_ + lch) * 16 + 1]);
      s_wn[RPC_ + 1] = cload(&g_hw[(b * CH_ + rch) * 16 + 0]);
    }
    if (wave == 1) {
      float d = (lane < CH_) ? cload(&g_se[(b * CH_ + lane) * 16]) : 0.f;
      d += __shfl_xor(d, 1); d += __shfl_xor(d, 2); d += __shfl_xor(d, 4);
      if (lane == 0) s_scal[7] = 1.0f / d;
    }
    __syncthreads();
    {
      const float invden = s_scal[7], gG = s_scal[1];
      const float sh0 = s_scal[2], sh1 = s_scal[3], sh2 = s_scal[4], gam = s_scal[5];
      float wgm = gG * s_es[tid]     * invden + (1.0f - gG) * s_wn[tid];
      float wg0 = gG * s_es[tid + 1] * invden + (1.0f - gG) * s_wn[tid + 1];
      float wgp = gG * s_es[tid + 2] * invden + (1.0f - gG) * s_wn[tid + 2];
      float what = sh0 * wgm + sh1 * wg0 + sh2 * wgp;
      wp_reg = expf(gam * logf(what));   // w_hat^gamma (unnormalized; carried to A')
      s_wpA[tid] = wp_reg;
      float acc = wp_reg;
      #pragma unroll
      for (int o = 32; o > 0; o >>= 1) acc += __shfl_xor(acc, o);
      if (lane == 0) s_red[wave] = acc;
    }
    __syncthreads();
    if (tid == 0) cstore(&g_sw[(b * CH_ + ch) * 16], s_red[0] + s_red[1] + s_red[2] + s_red[3]);
    {
      // rp'[m] = sum_rows wp*mem_old  (register butterfly)
      float v[16];
      #pragma unroll
      for (int j = 0; j < 16; ++j) v[j] = 0.f;
      #pragma unroll
      for (int k = 0; k < 4; ++k) {
        float wp = s_wpA[rb + 64 * k];
        #pragma unroll
        for (int j = 0; j < 16; ++j) v[j] += wp * mreg[k][j];
      }
      #pragma unroll
      for (int a = 0; a < 4; ++a) {
        const int bit = 2 + a;
        int myb = (lane >> bit) & 1;
        const int L = 16 >> (a + 1);
        float nv[8];
        #pragma unroll
        for (int j2 = 0; j2 < L; ++j2) {
          float keep = myb ? v[2 * j2 + 1] : v[2 * j2];
          float send = myb ? v[2 * j2]     : v[2 * j2 + 1];
          float got  = __shfl_xor(send, 1 << bit);
          nv[j2] = keep + got;
        }
        #pragma unroll
        for (int j2 = 0; j2 < L; ++j2) v[j2] = nv[j2];
      }
      s_rp[wave][16 * (lane & 3) + (lane >> 2)] = v[0];
    }
    __syncthreads();
    if (tid < M_) {
      float rv = s_rp[0][tid] + s_rp[1][tid] + s_rp[2][tid] + s_rp[3][tid];
      cstore(&g_rp[(b * CH_ + ch) * M_ + tid], rv);
    }
    gbar(flags, bar++, b, ch);
  }

  // ---------------- final: store mem registers to d_out tail ----------------
  {
    float* dst = membuf + ((size_t)b * N_ + n0) * M_;
    #pragma unroll
    for (int k = 0; k < 4; ++k) {
      #pragma unroll
      for (int f = 0; f < 4; ++f) {
        float4 vv = make_float4(mreg[k][4*f], mreg[k][4*f+1], mreg[k][4*f+2], mreg[k][4*f+3]);
        *(float4*)(dst + (rb + 64 * k) * M_ + q * 16 + 4 * f) = vv;
      }
    }
  }
}

extern "C" void kernel_launch(void* const* d_in, const int* in_sizes, int n_in,
                              void* d_out, int out_size, void* d_ws, size_t ws_size,
                              hipStream_t stream) {
  const float* x   = (const float*)d_in[0];
  const float* mem = (const float*)d_in[1];
  const float* w0  = (const float*)d_in[2];
  const float* r0  = (const float*)d_in[3];
  const float* h0  = (const float*)d_in[4];
  const float* c0  = (const float*)d_in[5];
  const float* Wih = (const float*)d_in[6];
  const float* Whh = (const float*)d_in[7];
  const float* bih = (const float*)d_in[8];
  const float* bhh = (const float*)d_in[9];
  const float* Wp  = (const float*)d_in[10];
  const float* bp  = (const float*)d_in[11];
  const float* Wfc = (const float*)d_in[12];
  const float* bfc = (const float*)d_in[13];
  float* out = (float*)d_out;
  float* wsp = (float*)d_ws;
  unsigned* flags = (unsigned*)((char*)d_ws + FLAG_BYTE_OFF);

  hipMemsetAsync((void*)flags, 0, FLAG_BYTES, stream);

  hipLaunchKernelGGL(ntm_kernel, dim3(NBLK_), dim3(NTHR_), 0, stream,
                     x, mem, w0, r0, h0, c0, Wih, Whh, bih, bhh,
                     Wp, bp, Wfc, bfc, out, wsp, flags);
}